// Round 1
// baseline (912.732 us; speedup 1.0000x reference)
//
#include <hip/hip_runtime.h>
#include <hip/hip_bf16.h>
#include <math.h>

typedef __hip_bfloat16 bf16;
typedef float f32x4 __attribute__((ext_vector_type(4)));
typedef short bf16x8 __attribute__((ext_vector_type(8)));

#define NNODES 4095
#define BATCH 64
#define NUM_OPS 20
#define TEMP 3.0f

// workspace layout (bytes)
#define OFF_WBIGT 0x000000ull              // 1280*640*2 = 1,638,400 B
#define OFF_BIAS  0x190000ull              // 1280*4
#define OFF_HA    0x200000ull              // 64 MiB  (levels 11,9,7,...)
#define OFF_CA    (OFF_HA + (64ull<<20))   // 64 MiB
#define OFF_HB    (OFF_CA + (64ull<<20))   // 32 MiB  (levels 10,8,...,0)
#define OFF_CB    (OFF_HB + (32ull<<20))   // 32 MiB
// total = 194 MiB

__device__ __forceinline__ float sigmoid_f(float x) {
    return 1.0f / (1.0f + __expf(-x));
}
__device__ __forceinline__ float tanh_f(float x) {
    // safe for large |x|: exp->inf gives 1, exp->0 gives -1 (no inf/inf)
    return 1.0f - 2.0f / (__expf(2.0f * x) + 1.0f);
}

// Build WbigT[n][k] (bf16, n in [0,1280), k in [0,640)) and biasCat[1280].
// k<128: x rows (Wiou | Wf dup); k in [128,384): even child; [384,640): odd child.
// n = g*256 + ch with gates g: 0=i,1=o,2=u,3=f0,4=f1.
__global__ void init_weights(const float* __restrict__ Wiou,
                             const float* __restrict__ biou,
                             const float* __restrict__ Uiou,
                             const float* __restrict__ Wf,
                             const float* __restrict__ bfv,
                             const float* __restrict__ Uf,
                             bf16* __restrict__ wbigT,
                             float* __restrict__ biasCat)
{
    int idx = blockIdx.x * 256 + threadIdx.x;
    if (idx < 1280 * 640) {
        int k = idx % 640;
        int n = idx / 640;
        int g = n >> 8;
        int ch = n & 255;
        float v;
        if (k < 128) {
            v = (g < 3) ? Wiou[k * 768 + n] : Wf[k * 256 + ch];
        } else {
            int par = (k < 384) ? 0 : 1;
            int hh = (k - 128) & 255;
            if (g < 3) v = Uiou[(par * 256 + hh) * 768 + n];
            else {
                int kk = g - 3;
                v = Uf[(((kk * 2 + par) * 256) + hh) * 256 + ch];
            }
        }
        wbigT[(size_t)n * 640 + k] = __float2bfloat16(v);
    }
    if (idx < 1280) {
        biasCat[idx] = (idx < 768) ? biou[idx] : bfv[idx & 255];
    }
}

// One tree level. Rows r = b*m + j (parents). A row = [x(128) | h_even | h_odd].
// Block: 128 rows x 32 channels (5 gate col-tiles per wave, spaced 256 apart),
// so each lane holds i,o,u,f0,f1 for its (row,ch) in registers -> fused epilogue.
template <bool LEAF>
__global__ __launch_bounds__(256, 2)
void level_kernel(const float* __restrict__ arg_hot,
                  const bf16* __restrict__ wbigT,
                  const float* __restrict__ biasCat,
                  const bf16* __restrict__ h_child,   // [(2M) rows][256]
                  const bf16* __restrict__ c_child,
                  bf16* __restrict__ h_out,           // [M rows][256]
                  bf16* __restrict__ c_out,
                  int m, int logm)
{
    constexpr int NG = LEAF ? 3 : 5;
    constexpr int K  = LEAF ? 128 : 640;
    constexpr int BK = 64;
    constexpr int KI = K / BK;

    const int M = BATCH * m;
    const int node_base = m - 1;

    __shared__ bf16 As[128][BK + 8];
    __shared__ bf16 Bs[NG * 32][BK + 8];

    const int tid = threadIdx.x;

    // block swizzle: co-locate the 8 ch-blocks sharing an A m-tile on one XCD,
    // temporally adjacent (same xcd slot, consecutive per-XCD sequence).
    int bid = blockIdx.x;
    int mtiles = gridDim.x >> 3;
    int mtile, chblk;
    if ((mtiles & 7) == 0) {
        int xcd = bid & 7;
        int seq = bid >> 3;
        chblk = seq & 7;
        mtile = ((seq >> 3) << 3) + xcd;
    } else {
        mtile = bid >> 3;
        chblk = bid & 7;
    }
    const int rbase  = mtile * 128;
    const int chbase = chblk * 32;

    const int lane = tid & 63;
    const int wave = tid >> 6;
    const int wr = wave & 1;   // row half (64 rows)
    const int wc = wave >> 1;  // channel half (16 ch)
    const int l15 = lane & 15;
    const int lq  = lane >> 4;

    f32x4 acc[4][NG];
#pragma unroll
    for (int a = 0; a < 4; ++a)
#pragma unroll
        for (int g = 0; g < NG; ++g)
            acc[a][g] = (f32x4){0.f, 0.f, 0.f, 0.f};

    const int a_row0 = tid >> 2;          // 4 threads per row
    const int a_col0 = (tid & 3) * 16;    // 16 elems per thread

    for (int kb = 0; kb < KI; ++kb) {
        // ---- stage A: 128 x 64 bf16 ----
#pragma unroll
        for (int pass = 0; pass < 2; ++pass) {
            int row  = a_row0 + pass * 64;
            int r    = rbase + row;
            int kcol = kb * BK + a_col0;
            int4 w0, w1;
            if (r < M) {
                if (LEAF || kb < 2) {  // x region (fp32 -> bf16)
                    const float* src = arg_hot +
                        ((size_t)(r >> logm) * NNODES + node_base + (r & (m - 1))) * 128 + kcol;
                    alignas(16) bf16 tmp[16];
#pragma unroll
                    for (int u = 0; u < 16; ++u) tmp[u] = __float2bfloat16(src[u]);
                    w0 = *(const int4*)&tmp[0];
                    w1 = *(const int4*)&tmp[8];
                } else {               // h region (bf16 passthrough)
                    const bf16* src = h_child + (size_t)r * 512 + (kcol - 128);
                    w0 = *(const int4*)src;
                    w1 = *(const int4*)(src + 8);
                }
            } else {
                w0 = make_int4(0, 0, 0, 0);
                w1 = make_int4(0, 0, 0, 0);
            }
            *(int4*)&As[row][a_col0]     = w0;
            *(int4*)&As[row][a_col0 + 8] = w1;
        }
        // ---- stage B (transposed weights): NG*32 rows x 64 k ----
#pragma unroll
        for (int t = 0; t < NG; ++t) {
            int flat = tid + t * 256;        // 0 .. NG*256-1
            int brow = flat >> 3;            // Bs row: g*32 + cl
            int col8 = (flat & 7) * 8;       // k offset within BK
            int g  = brow >> 5;
            int cl = brow & 31;
            const bf16* src = wbigT + (size_t)(g * 256 + chbase + cl) * 640 + kb * BK + col8;
            *(int4*)&Bs[brow][col8] = *(const int4*)src;
        }
        __syncthreads();
        // ---- compute: 2 k-steps of 32, 4x NG MFMAs ----
#pragma unroll
        for (int ks = 0; ks < 2; ++ks) {
            int k0 = ks * 32 + lq * 8;
            bf16x8 af[4];
#pragma unroll
            for (int rt = 0; rt < 4; ++rt)
                af[rt] = *(const bf16x8*)&As[wr * 64 + rt * 16 + l15][k0];
#pragma unroll
            for (int g = 0; g < NG; ++g) {
                bf16x8 bfr = *(const bf16x8*)&Bs[g * 32 + wc * 16 + l15][k0];
#pragma unroll
                for (int rt = 0; rt < 4; ++rt)
                    acc[rt][g] = __builtin_amdgcn_mfma_f32_16x16x32_bf16(
                        af[rt], bfr, acc[rt][g], 0, 0, 0);
            }
        }
        __syncthreads();
    }

    // ---- fused LSTM-cell epilogue (all gates in-register per lane) ----
    const int ch = chbase + wc * 16 + l15;
    const float b_i = biasCat[ch];
    const float b_o = biasCat[256 + ch];
    const float b_u = biasCat[512 + ch];
    const float b_f = LEAF ? 0.f : biasCat[768 + ch];

#pragma unroll
    for (int rt = 0; rt < 4; ++rt) {
#pragma unroll
        for (int ri = 0; ri < 4; ++ri) {
            int r = rbase + wr * 64 + rt * 16 + lq * 4 + ri;
            if (r < M) {
                float i = sigmoid_f(acc[rt][0][ri] + b_i);
                float o = sigmoid_f(acc[rt][1][ri] + b_o);
                float u = tanh_f(acc[rt][2][ri] + b_u);
                float cn;
                if (LEAF) {
                    cn = i * u;
                } else {
                    float f0 = sigmoid_f(acc[rt][3][ri] + b_f);
                    float f1 = sigmoid_f(acc[rt][4][ri] + b_f);
                    float c0 = __bfloat162float(c_child[(size_t)r * 512 + ch]);
                    float c1 = __bfloat162float(c_child[(size_t)r * 512 + 256 + ch]);
                    cn = i * u + f0 * c0 + f1 * c1;
                }
                float h = o * tanh_f(cn);
                h_out[(size_t)r * 256 + ch] = __float2bfloat16(h);
                c_out[(size_t)r * 256 + ch] = __float2bfloat16(cn);
            }
        }
    }
}

// actor head: logits = log(mask) + (h.w + b)*mask; softmax(logits/TEMP)
__global__ void head_kernel(const bf16* __restrict__ rootH,
                            const float* __restrict__ actor_w,
                            const float* __restrict__ actor_b,
                            const float* __restrict__ vmask,
                            float* __restrict__ out)
{
    int b = blockIdx.x;
    __shared__ float logits[NUM_OPS];
    int t = threadIdx.x;
    if (t < NUM_OPS) {
        const bf16* hr = rootH + b * 256;
        const float* w = actor_w + t * 256;
        float dot = 0.f;
        for (int hh = 0; hh < 256; ++hh)
            dot += __bfloat162float(hr[hh]) * w[hh];
        float mk = vmask[b * NUM_OPS + t];
        float lg = (mk > 0.f) ? (logf(mk) + (dot + actor_b[t]) * mk) : -INFINITY;
        logits[t] = lg / TEMP;
    }
    __syncthreads();
    if (t == 0) {
        float mx = -INFINITY;
        for (int o = 0; o < NUM_OPS; ++o) mx = fmaxf(mx, logits[o]);
        float s = 0.f;
        float e[NUM_OPS];
        for (int o = 0; o < NUM_OPS; ++o) { e[o] = __expf(logits[o] - mx); s += e[o]; }
        float inv = 1.f / s;
        for (int o = 0; o < NUM_OPS; ++o) out[b * NUM_OPS + o] = e[o] * inv;
    }
}

extern "C" void kernel_launch(void* const* d_in, const int* in_sizes, int n_in,
                              void* d_out, int out_size, void* d_ws, size_t ws_size,
                              hipStream_t stream)
{
    const float* arg_hot = (const float*)d_in[0];
    const float* Wiou    = (const float*)d_in[1];
    const float* biou    = (const float*)d_in[2];
    const float* Uiou    = (const float*)d_in[3];
    const float* Wf      = (const float*)d_in[4];
    const float* bfv     = (const float*)d_in[5];
    const float* Uf      = (const float*)d_in[6];
    const float* actor_w = (const float*)d_in[7];
    const float* actor_b = (const float*)d_in[8];
    const float* vmask   = (const float*)d_in[9];

    char* ws = (char*)d_ws;
    bf16*  wbigT   = (bf16*)(ws + OFF_WBIGT);
    float* biasCat = (float*)(ws + OFF_BIAS);
    bf16*  hA = (bf16*)(ws + OFF_HA);
    bf16*  cA = (bf16*)(ws + OFF_CA);
    bf16*  hB = (bf16*)(ws + OFF_HB);
    bf16*  cB = (bf16*)(ws + OFF_CB);

    init_weights<<<dim3((1280 * 640 + 255) / 256), 256, 0, stream>>>(
        Wiou, biou, Uiou, Wf, bfv, Uf, wbigT, biasCat);

    // leaf level (l=11): m=2048, K=128, writes buffers A
    {
        int m = 2048;
        int mtiles = (BATCH * m + 127) / 128;   // 1024
        level_kernel<true><<<dim3(mtiles * 8), 256, 0, stream>>>(
            arg_hot, wbigT, biasCat, nullptr, nullptr, hA, cA, m, 11);
    }
    // interior levels 10..0
    for (int l = 10; l >= 0; --l) {
        int m = 1 << l;
        int mtiles = (BATCH * m + 127) / 128;
        bf16 *hc, *cc, *ho, *co;
        if (l & 1) { hc = hB; cc = cB; ho = hA; co = cA; }
        else       { hc = hA; cc = cA; ho = hB; co = cB; }
        level_kernel<false><<<dim3(mtiles * 8), 256, 0, stream>>>(
            arg_hot, wbigT, biasCat, hc, cc, ho, co, m, l);
    }
    // root h is in hB (level 0 writes B)
    head_kernel<<<dim3(BATCH), 64, 0, stream>>>(hB, actor_w, actor_b, vmask, (float*)d_out);
}